// Round 1
// baseline (949.766 us; speedup 1.0000x reference)
//
#include <hip/hip_runtime.h>
#include <hip/hip_bf16.h>
#include <math.h>
#include <stdint.h>

#define S_TOK 8192
#define D_DIM 1024
#define F_DIM 4096
#define E_EXP 8
#define C_CAP 2560   // int(1.25 * 8192 * 2 / 8)

typedef __bf16 bf16x8_t __attribute__((ext_vector_type(8)));
typedef __bf16 bf16x4_t __attribute__((ext_vector_type(4)));
typedef float f32x4_t __attribute__((ext_vector_type(4)));

// async global->LDS, 16B per lane; LDS dest = wave-uniform base + lane*16
__device__ __forceinline__ void async_copy16(const void* g, void* l) {
  __builtin_amdgcn_global_load_lds(
      (const __attribute__((address_space(1))) unsigned int*)g,
      (__attribute__((address_space(3))) unsigned int*)l, 16, 0, 0);
}

// ---------------- routing: logits -> softmax -> top2; also emits x_bf16 ----------------
__global__ __launch_bounds__(256) void routing_kernel(
    const float* __restrict__ x, const float* __restrict__ wg,
    __bf16* __restrict__ x_bf, int* __restrict__ asg_e, float* __restrict__ asg_g,
    float* __restrict__ imp_sum)
{
  __shared__ float s_imp[E_EXP];
  const int tid = threadIdx.x, lane = tid & 63, w = tid >> 6;
  if (tid < E_EXP) s_imp[tid] = 0.f;
  __syncthreads();
  const int t = blockIdx.x * 4 + w;   // one wave per token

  const float4* xp = (const float4*)(x + (size_t)t * D_DIM);
  float4 xv[4];
#pragma unroll
  for (int j = 0; j < 4; j++) xv[j] = xp[lane + 64 * j];

  // free bf16 conversion of x (needed by GEMM1)
#pragma unroll
  for (int j = 0; j < 4; j++) {
    bf16x4_t o;
    o[0] = (__bf16)xv[j].x; o[1] = (__bf16)xv[j].y;
    o[2] = (__bf16)xv[j].z; o[3] = (__bf16)xv[j].w;
    *(bf16x4_t*)(x_bf + (size_t)t * D_DIM + (size_t)(lane + 64 * j) * 4) = o;
  }

  float acc[E_EXP];
#pragma unroll
  for (int e = 0; e < E_EXP; e++) acc[e] = 0.f;
#pragma unroll
  for (int e = 0; e < E_EXP; e++) {
    const float4* wp = (const float4*)(wg + (size_t)e * D_DIM);
#pragma unroll
    for (int j = 0; j < 4; j++) {
      const float4 wv = wp[lane + 64 * j];
      acc[e] += xv[j].x * wv.x + xv[j].y * wv.y + xv[j].z * wv.z + xv[j].w * wv.w;
    }
  }
#pragma unroll
  for (int e = 0; e < E_EXP; e++)
    for (int off = 32; off > 0; off >>= 1) acc[e] += __shfl_xor(acc[e], off);

  if (lane == 0) {
    float m = acc[0];
#pragma unroll
    for (int e = 1; e < E_EXP; e++) m = fmaxf(m, acc[e]);
    float p[E_EXP], s = 0.f;
#pragma unroll
    for (int e = 0; e < E_EXP; e++) { p[e] = expf(acc[e] - m); s += p[e]; }
    const float inv = 1.f / s;
#pragma unroll
    for (int e = 0; e < E_EXP; e++) p[e] *= inv;
    // top-2, first-index wins ties (matches lax.top_k)
    int e0 = 0; float v0 = p[0];
#pragma unroll
    for (int e = 1; e < E_EXP; e++) if (p[e] > v0) { v0 = p[e]; e0 = e; }
    int e1 = -1; float v1 = -1.f;
#pragma unroll
    for (int e = 0; e < E_EXP; e++) if (e != e0 && p[e] > v1) { v1 = p[e]; e1 = e; }
    asg_e[2 * t] = e0; asg_g[2 * t] = v0;
    asg_e[2 * t + 1] = e1; asg_g[2 * t + 1] = v1;
#pragma unroll
    for (int e = 0; e < E_EXP; e++) atomicAdd(&s_imp[e], p[e]);
  }
  __syncthreads();
  if (tid < E_EXP) atomicAdd(&imp_sum[tid], s_imp[tid]);
}

// ---------------- fp32 -> bf16 weight conversion ----------------
__global__ __launch_bounds__(256) void cvt_kernel(const float* __restrict__ src,
                                                  __bf16* __restrict__ dst, int n4)
{
  const int stride = gridDim.x * blockDim.x;
  for (int i = blockIdx.x * blockDim.x + threadIdx.x; i < n4; i += stride) {
    const float4 v = ((const float4*)src)[i];
    bf16x4_t o;
    o[0] = (__bf16)v.x; o[1] = (__bf16)v.y; o[2] = (__bf16)v.z; o[3] = (__bf16)v.w;
    ((bf16x4_t*)dst)[i] = o;
  }
}

// ---------------- positions: ordered per-expert scan + slot tables + aux ----------------
__global__ __launch_bounds__(256) void positions_kernel(
    const int* __restrict__ asg_e, const float* __restrict__ asg_g,
    const float* __restrict__ imp_sum, int* __restrict__ slot_token,
    float* __restrict__ slot_gate, int* __restrict__ cnt_g, float* __restrict__ aux_out)
{
  __shared__ int lcnt[E_EXP * 256];
  __shared__ int tot[E_EXP];
  const int tid = threadIdx.x;
  for (int i = tid; i < E_EXP * C_CAP; i += 256) slot_token[i] = -1;
  int cnt[E_EXP];
#pragma unroll
  for (int e = 0; e < E_EXP; e++) cnt[e] = 0;
  const int a0 = tid * 64;   // 16384 assignments / 256 threads
  for (int j = 0; j < 64; j++) cnt[asg_e[a0 + j]]++;
#pragma unroll
  for (int e = 0; e < E_EXP; e++) lcnt[e * 256 + tid] = cnt[e];
  __syncthreads();
  if (tid < E_EXP) {   // exclusive prefix per expert (serial 256: cheap)
    int run = 0;
    for (int i = 0; i < 256; i++) { const int v = lcnt[tid * 256 + i]; lcnt[tid * 256 + i] = run; run += v; }
    tot[tid] = run;
    cnt_g[tid] = run;
  }
  __syncthreads();
  int base[E_EXP];
#pragma unroll
  for (int e = 0; e < E_EXP; e++) base[e] = lcnt[e * 256 + tid];
  for (int j = 0; j < 64; j++) {
    const int a = a0 + j;
    const int e = asg_e[a];
    const int pp = base[e]++;
    if (pp < C_CAP) { slot_token[e * C_CAP + pp] = a >> 1; slot_gate[e * C_CAP + pp] = asg_g[a]; }
  }
  if (tid == 0) {
    float aux = 0.f;
#pragma unroll
    for (int e = 0; e < E_EXP; e++) aux += imp_sum[e] * (float)tot[e];
    aux_out[0] = (float)E_EXP * aux / ((float)S_TOK * (float)S_TOK);
  }
}

// ---------------- grouped GEMM (m97 structure, 128x128xBK64, 4 waves of 64x64) ----------
// MODE 0: H = gelu(gather(x_bf) @ W1[e]^T + b1)        (NT: A[M,K], B[N,K], K=D, N=F)
// MODE 1: y[tok] += g * (H @ W2[e]^T + b2 + x[tok])    (K=F, N=D, atomic combine)
template <int MODE>
__global__ __launch_bounds__(256, 2) void moe_gemm(
    const __bf16* __restrict__ A, const __bf16* __restrict__ Bw,
    const float* __restrict__ bias, const int* __restrict__ slot_token,
    const float* __restrict__ slot_gate, const float* __restrict__ xres,
    const int* __restrict__ cnt, __bf16* __restrict__ Hout, float* __restrict__ y,
    int MT, int NT, int N, int K)
{
  const int bid = blockIdx.x;
  const int e = bid / (MT * NT);
  const int r0 = bid % (MT * NT);
  const int mt = r0 / NT, nt = r0 % NT;
  const int m0 = mt * 128, n0 = nt * 128;
  if (m0 >= cnt[e]) return;   // whole tile beyond this expert's occupancy

  const int tid = threadIdx.x, lane = tid & 63, w = tid >> 6;
  const int wm = w >> 1, wn = w & 1;

  __shared__ __align__(16) unsigned short sA[128 * 64];   // 16 KB
  __shared__ __align__(16) unsigned short sB[128 * 64];   // 16 KB

  const int rstage = lane >> 3;   // 8 rows per wave-instruction
  const int cstage = lane & 7;    // 16B chunk within 128B row

  const char* gA[4];
  const char* gB[4];
  void* lA[4];
  void* lB[4];
#pragma unroll
  for (int i = 0; i < 4; i++) {
    const int rowA = w * 32 + i * 8 + rstage;
    size_t arow;
    if (MODE == 0) {
      int tok = slot_token[e * C_CAP + m0 + rowA];
      if (tok < 0) tok = 0;   // empty slot: load junk row 0, epilogue-discarded downstream
      arow = (size_t)tok * (size_t)K;
    } else {
      arow = ((size_t)(e * C_CAP + m0 + rowA)) * (size_t)K;
    }
    gA[i] = (const char*)(A + arow) + cstage * 16;
    lA[i] = (void*)&sA[(w * 32 + i * 8) * 64];
    const int rowB = w * 32 + i * 8 + rstage;
    const size_t brow = ((size_t)(e * N + n0 + rowB)) * (size_t)K;
    gB[i] = (const char*)(Bw + brow) + cstage * 16;
    lB[i] = (void*)&sB[(w * 32 + i * 8) * 64];
  }

  f32x4_t acc[4][4];
#pragma unroll
  for (int mi = 0; mi < 4; mi++)
#pragma unroll
    for (int ni = 0; ni < 4; ni++) acc[mi][ni] = (f32x4_t){0.f, 0.f, 0.f, 0.f};

  for (int k0 = 0; k0 < K; k0 += 64) {
    const size_t koff = (size_t)k0 * 2;
    __syncthreads();
#pragma unroll
    for (int i = 0; i < 4; i++) async_copy16(gA[i] + koff, lA[i]);
#pragma unroll
    for (int i = 0; i < 4; i++) async_copy16(gB[i] + koff, lB[i]);
    __syncthreads();   // compiler drains vmcnt here
#pragma unroll
    for (int kk = 0; kk < 2; kk++) {
      bf16x8_t af[4], bfv[4];
#pragma unroll
      for (int mi = 0; mi < 4; mi++)
        af[mi] = *(const bf16x8_t*)&sA[(wm * 64 + mi * 16 + (lane & 15)) * 64 + kk * 32 + (lane >> 4) * 8];
#pragma unroll
      for (int ni = 0; ni < 4; ni++)
        bfv[ni] = *(const bf16x8_t*)&sB[(wn * 64 + ni * 16 + (lane & 15)) * 64 + kk * 32 + (lane >> 4) * 8];
#pragma unroll
      for (int mi = 0; mi < 4; mi++)
#pragma unroll
        for (int ni = 0; ni < 4; ni++)
          acc[mi][ni] = __builtin_amdgcn_mfma_f32_16x16x32_bf16(af[mi], bfv[ni], acc[mi][ni], 0, 0, 0);
    }
  }

  // C/D layout: col = lane&15, row = (lane>>4)*4 + reg  (m89-verified)
  const int col_lo = lane & 15;
  const int row_hi = (lane >> 4) * 4;
  if (MODE == 0) {
#pragma unroll
    for (int ni = 0; ni < 4; ni++) {
      const int gcol = n0 + wn * 64 + ni * 16 + col_lo;
      const float bv = bias[e * N + gcol];
#pragma unroll
      for (int mi = 0; mi < 4; mi++) {
#pragma unroll
        for (int r = 0; r < 4; r++) {
          const int grow = m0 + wm * 64 + mi * 16 + row_hi + r;
          const float v = acc[mi][ni][r] + bv;
          const float gl = 0.5f * v * (1.0f + erff(v * 0.70710678118654752f));  // exact gelu
          Hout[((size_t)(e * C_CAP + grow)) * (size_t)N + gcol] = (__bf16)gl;
        }
      }
    }
  } else {
#pragma unroll
    for (int mi = 0; mi < 4; mi++) {
#pragma unroll
      for (int r = 0; r < 4; r++) {
        const int slot = e * C_CAP + m0 + wm * 64 + mi * 16 + row_hi + r;
        const int tok = slot_token[slot];
        if (tok < 0) continue;
        const float g = slot_gate[slot];
        const size_t trow = (size_t)tok * (size_t)N;
#pragma unroll
        for (int ni = 0; ni < 4; ni++) {
          const int gcol = n0 + wn * 64 + ni * 16 + col_lo;
          const float v = acc[mi][ni][r] + bias[e * N + gcol] + xres[trow + gcol];
          atomicAdd(&y[trow + gcol], g * v);   // <=2 adds per element
        }
      }
    }
  }
}

extern "C" void kernel_launch(void* const* d_in, const int* in_sizes, int n_in,
                              void* d_out, int out_size, void* d_ws, size_t ws_size,
                              hipStream_t stream) {
  const float* x  = (const float*)d_in[0];
  const float* wg = (const float*)d_in[1];
  const float* W1 = (const float*)d_in[2];
  const float* b1 = (const float*)d_in[3];
  const float* W2 = (const float*)d_in[4];
  const float* b2 = (const float*)d_in[5];
  float* y = (float*)d_out;

  // workspace layout (~320 MB)
  char* p = (char*)d_ws;
  __bf16* x_bf = (__bf16*)p;    p += (size_t)S_TOK * D_DIM * 2;
  __bf16* w1_bf = (__bf16*)p;   p += (size_t)E_EXP * F_DIM * D_DIM * 2;
  __bf16* w2_bf = (__bf16*)p;   p += (size_t)E_EXP * F_DIM * D_DIM * 2;
  __bf16* Hbuf = (__bf16*)p;    p += (size_t)E_EXP * C_CAP * F_DIM * 2;
  int* slot_token = (int*)p;    p += (size_t)E_EXP * C_CAP * 4;
  float* slot_gate = (float*)p; p += (size_t)E_EXP * C_CAP * 4;
  int* asg_e = (int*)p;         p += (size_t)S_TOK * 2 * 4;
  float* asg_g = (float*)p;     p += (size_t)S_TOK * 2 * 4;
  float* imp_sum = (float*)p;   p += 64;
  int* cnt_g = (int*)p;         p += 64;

  hipMemsetAsync(d_out, 0, ((size_t)S_TOK * D_DIM + 1) * sizeof(float), stream);
  hipMemsetAsync(imp_sum, 0, E_EXP * sizeof(float), stream);

  routing_kernel<<<S_TOK / 4, 256, 0, stream>>>(x, wg, x_bf, asg_e, asg_g, imp_sum);
  cvt_kernel<<<2048, 256, 0, stream>>>(W1, w1_bf, E_EXP * F_DIM * D_DIM / 4);
  cvt_kernel<<<2048, 256, 0, stream>>>(W2, w2_bf, E_EXP * F_DIM * D_DIM / 4);
  positions_kernel<<<1, 256, 0, stream>>>(asg_e, asg_g, imp_sum, slot_token, slot_gate,
                                          cnt_g, y + (size_t)S_TOK * D_DIM);
  moe_gemm<0><<<E_EXP * 20 * 32, 256, 0, stream>>>(x_bf, w1_bf, b1, slot_token, nullptr, nullptr,
                                                   cnt_g, Hbuf, nullptr, 20, 32, F_DIM, D_DIM);
  moe_gemm<1><<<E_EXP * 20 * 8, 256, 0, stream>>>(Hbuf, w2_bf, b2, slot_token, slot_gate, x,
                                                  cnt_g, nullptr, y, 20, 8, D_DIM, F_DIM);
}

// Round 2
// 883.558 us; speedup vs baseline: 1.0749x; 1.0749x over previous
//
#include <hip/hip_runtime.h>
#include <hip/hip_bf16.h>
#include <math.h>
#include <stdint.h>

#define S_TOK 8192
#define D_DIM 1024
#define F_DIM 4096
#define E_EXP 8
#define C_CAP 2560   // int(1.25 * 8192 * 2 / 8)

typedef __bf16 bf16x8_t __attribute__((ext_vector_type(8)));
typedef __bf16 bf16x4_t __attribute__((ext_vector_type(4)));
typedef float f32x4_t __attribute__((ext_vector_type(4)));

// async global->LDS, 16B per lane; LDS dest = wave-uniform base + lane*16
__device__ __forceinline__ void async_copy16(const void* g, void* l) {
  __builtin_amdgcn_global_load_lds(
      (const __attribute__((address_space(1))) unsigned int*)g,
      (__attribute__((address_space(3))) unsigned int*)l, 16, 0, 0);
}

// ---------------- routing: logits -> softmax -> top2; also emits x_bf16 ----------------
__global__ __launch_bounds__(256) void routing_kernel(
    const float* __restrict__ x, const float* __restrict__ wg,
    __bf16* __restrict__ x_bf, int* __restrict__ asg_e, float* __restrict__ asg_g,
    float* __restrict__ imp_sum)
{
  __shared__ float s_imp[E_EXP];
  const int tid = threadIdx.x, lane = tid & 63, w = tid >> 6;
  if (tid < E_EXP) s_imp[tid] = 0.f;
  __syncthreads();
  const int t = blockIdx.x * 4 + w;   // one wave per token

  const float4* xp = (const float4*)(x + (size_t)t * D_DIM);
  float4 xv[4];
#pragma unroll
  for (int j = 0; j < 4; j++) xv[j] = xp[lane + 64 * j];

  // free bf16 conversion of x (needed by GEMM1)
#pragma unroll
  for (int j = 0; j < 4; j++) {
    bf16x4_t o;
    o[0] = (__bf16)xv[j].x; o[1] = (__bf16)xv[j].y;
    o[2] = (__bf16)xv[j].z; o[3] = (__bf16)xv[j].w;
    *(bf16x4_t*)(x_bf + (size_t)t * D_DIM + (size_t)(lane + 64 * j) * 4) = o;
  }

  float acc[E_EXP];
#pragma unroll
  for (int e = 0; e < E_EXP; e++) acc[e] = 0.f;
#pragma unroll
  for (int e = 0; e < E_EXP; e++) {
    const float4* wp = (const float4*)(wg + (size_t)e * D_DIM);
#pragma unroll
    for (int j = 0; j < 4; j++) {
      const float4 wv = wp[lane + 64 * j];
      acc[e] += xv[j].x * wv.x + xv[j].y * wv.y + xv[j].z * wv.z + xv[j].w * wv.w;
    }
  }
#pragma unroll
  for (int e = 0; e < E_EXP; e++)
    for (int off = 32; off > 0; off >>= 1) acc[e] += __shfl_xor(acc[e], off);

  if (lane == 0) {
    float m = acc[0];
#pragma unroll
    for (int e = 1; e < E_EXP; e++) m = fmaxf(m, acc[e]);
    float p[E_EXP], s = 0.f;
#pragma unroll
    for (int e = 0; e < E_EXP; e++) { p[e] = expf(acc[e] - m); s += p[e]; }
    const float inv = 1.f / s;
#pragma unroll
    for (int e = 0; e < E_EXP; e++) p[e] *= inv;
    // top-2, first-index wins ties (matches lax.top_k)
    int e0 = 0; float v0 = p[0];
#pragma unroll
    for (int e = 1; e < E_EXP; e++) if (p[e] > v0) { v0 = p[e]; e0 = e; }
    int e1 = -1; float v1 = -1.f;
#pragma unroll
    for (int e = 0; e < E_EXP; e++) if (e != e0 && p[e] > v1) { v1 = p[e]; e1 = e; }
    asg_e[2 * t] = e0; asg_g[2 * t] = v0;
    asg_e[2 * t + 1] = e1; asg_g[2 * t + 1] = v1;
#pragma unroll
    for (int e = 0; e < E_EXP; e++) atomicAdd(&s_imp[e], p[e]);
  }
  __syncthreads();
  if (tid < E_EXP) atomicAdd(&imp_sum[tid], s_imp[tid]);
}

// ---------------- fp32 -> bf16 weight conversion (W1 and W2 in one launch) ------------
__global__ __launch_bounds__(256) void cvt_kernel(const float* __restrict__ src,
                                                  __bf16* __restrict__ dst, int n4)
{
  const int stride = gridDim.x * blockDim.x;
  for (int i = blockIdx.x * blockDim.x + threadIdx.x; i < n4; i += stride) {
    const float4 v = ((const float4*)src)[i];
    bf16x4_t o;
    o[0] = (__bf16)v.x; o[1] = (__bf16)v.y; o[2] = (__bf16)v.z; o[3] = (__bf16)v.w;
    ((bf16x4_t*)dst)[i] = o;
  }
}

// ---------------- positions: ordered per-expert scan + slot tables + aux ----------------
__global__ __launch_bounds__(256) void positions_kernel(
    const int* __restrict__ asg_e, const float* __restrict__ asg_g,
    const float* __restrict__ imp_sum, int* __restrict__ slot_token,
    float* __restrict__ slot_gate, int* __restrict__ cnt_g, float* __restrict__ aux_out)
{
  __shared__ int lcnt[E_EXP * 256];
  __shared__ int tot[E_EXP];
  const int tid = threadIdx.x;
  for (int i = tid; i < E_EXP * C_CAP; i += 256) slot_token[i] = -1;
  int cnt[E_EXP];
#pragma unroll
  for (int e = 0; e < E_EXP; e++) cnt[e] = 0;
  const int a0 = tid * 64;   // 16384 assignments / 256 threads
  for (int j = 0; j < 64; j++) cnt[asg_e[a0 + j]]++;
#pragma unroll
  for (int e = 0; e < E_EXP; e++) lcnt[e * 256 + tid] = cnt[e];
  __syncthreads();
  if (tid < E_EXP) {   // exclusive prefix per expert (serial 256: cheap)
    int run = 0;
    for (int i = 0; i < 256; i++) { const int v = lcnt[tid * 256 + i]; lcnt[tid * 256 + i] = run; run += v; }
    tot[tid] = run;
    cnt_g[tid] = run;
  }
  __syncthreads();
  int base[E_EXP];
#pragma unroll
  for (int e = 0; e < E_EXP; e++) base[e] = lcnt[e * 256 + tid];
  for (int j = 0; j < 64; j++) {
    const int a = a0 + j;
    const int e = asg_e[a];
    const int pp = base[e]++;
    if (pp < C_CAP) { slot_token[e * C_CAP + pp] = a >> 1; slot_gate[e * C_CAP + pp] = asg_g[a]; }
  }
  if (tid == 0) {
    float aux = 0.f;
#pragma unroll
    for (int e = 0; e < E_EXP; e++) aux += imp_sum[e] * (float)tot[e];
    aux_out[0] = (float)E_EXP * aux / ((float)S_TOK * (float)S_TOK);
  }
}

// ---------------- grouped GEMM (128x128xBK64, 4 waves of 64x64, XOR-swizzled LDS) ------
// LDS physical layout: row-major 128 rows x 128 B; within a row, 16B chunk p holds
// logical chunk (p ^ (row&7)).  Staging applies the swizzle on the GLOBAL source
// address (global_load_lds dest is pinned to base+lane*16); reads de-swizzle.
// MODE 0: H = gelu(gather(x_bf) @ W1[e]^T + b1)        (K=D, N=F)
// MODE 1: y[tok] += g * (H @ W2[e]^T + b2 + x[tok])    (K=F, N=D, atomic combine)
template <int MODE>
__global__ __launch_bounds__(256, 3) void moe_gemm(
    const __bf16* __restrict__ A, const __bf16* __restrict__ Bw,
    const float* __restrict__ bias, const int* __restrict__ slot_token,
    const float* __restrict__ slot_gate, const float* __restrict__ xres,
    const int* __restrict__ cnt, __bf16* __restrict__ Hout, float* __restrict__ y,
    int MT, int NT, int N, int K)
{
  // per-XCD contiguous tiles + 4-row group swizzle for L2 locality
  const int ntiles = gridDim.x;
  const int xcd = blockIdx.x & 7, slot = blockIdx.x >> 3;
  const int tile = xcd * (ntiles >> 3) + slot;
  const int e = tile / (MT * NT);
  const int t = tile % (MT * NT);
  const int grp = t / (4 * NT), rem = t % (4 * NT);
  const int mt = grp * 4 + (rem & 3), nt = rem >> 2;
  const int m0 = mt * 128, n0 = nt * 128;
  if (m0 >= cnt[e]) return;   // whole tile beyond this expert's occupancy

  const int tid = threadIdx.x, lane = tid & 63, w = tid >> 6;
  const int wm = w >> 1, wn = w & 1;

  __shared__ __align__(16) unsigned short sA[128 * 64];   // 16 KB
  __shared__ __align__(16) unsigned short sB[128 * 64];   // 16 KB

  const int rstage = lane >> 3;            // row within 8-row stage group (== row&7)
  const int cstage = (lane & 7) ^ rstage;  // XOR-swizzled 16B chunk to fetch

  const char* gA[4];
  const char* gB[4];
  void* lA[4];
  void* lB[4];
#pragma unroll
  for (int i = 0; i < 4; i++) {
    const int rowA = w * 32 + i * 8 + rstage;
    size_t arow;
    if (MODE == 0) {
      int tok = slot_token[e * C_CAP + m0 + rowA];
      if (tok < 0) tok = 0;   // empty slot: junk row 0, epilogue-discarded downstream
      arow = (size_t)tok * (size_t)K;
    } else {
      arow = ((size_t)(e * C_CAP + m0 + rowA)) * (size_t)K;
    }
    gA[i] = (const char*)(A + arow) + cstage * 16;
    lA[i] = (void*)&sA[(w * 32 + i * 8) * 64];
    const int rowB = w * 32 + i * 8 + rstage;
    const size_t brow = ((size_t)(e * N + n0 + rowB)) * (size_t)K;
    gB[i] = (const char*)(Bw + brow) + cstage * 16;
    lB[i] = (void*)&sB[(w * 32 + i * 8) * 64];
  }

  f32x4_t acc[4][4];
#pragma unroll
  for (int mi = 0; mi < 4; mi++)
#pragma unroll
    for (int ni = 0; ni < 4; ni++) acc[mi][ni] = (f32x4_t){0.f, 0.f, 0.f, 0.f};

  // de-swizzled LDS read offsets (halfs): row*64 + ((chunk ^ (row&7))*8)
  const int fr = lane & 15;          // fragment row within 16
  const int fq = lane >> 4;          // quadrant -> k chunk
  for (int k0 = 0; k0 < K; k0 += 64) {
    const size_t koff = (size_t)k0 * 2;
    __syncthreads();
#pragma unroll
    for (int i = 0; i < 4; i++) async_copy16(gA[i] + koff, lA[i]);
#pragma unroll
    for (int i = 0; i < 4; i++) async_copy16(gB[i] + koff, lB[i]);
    __syncthreads();   // drains vmcnt
#pragma unroll
    for (int kk = 0; kk < 2; kk++) {
      bf16x8_t af[4], bfv[4];
#pragma unroll
      for (int mi = 0; mi < 4; mi++) {
        const int row = wm * 64 + mi * 16 + fr;
        const int chk = (kk * 4 + fq) ^ (row & 7);
        af[mi] = *(const bf16x8_t*)&sA[row * 64 + chk * 8];
      }
#pragma unroll
      for (int ni = 0; ni < 4; ni++) {
        const int row = wn * 64 + ni * 16 + fr;
        const int chk = (kk * 4 + fq) ^ (row & 7);
        bfv[ni] = *(const bf16x8_t*)&sB[row * 64 + chk * 8];
      }
#pragma unroll
      for (int mi = 0; mi < 4; mi++)
#pragma unroll
        for (int ni = 0; ni < 4; ni++)
          acc[mi][ni] = __builtin_amdgcn_mfma_f32_16x16x32_bf16(af[mi], bfv[ni], acc[mi][ni], 0, 0, 0);
    }
  }

  // C/D layout: col = lane&15, row = (lane>>4)*4 + reg  (m89-verified)
  const int col_lo = lane & 15;
  const int row_hi = (lane >> 4) * 4;
  if (MODE == 0) {
#pragma unroll
    for (int ni = 0; ni < 4; ni++) {
      const int gcol = n0 + wn * 64 + ni * 16 + col_lo;
      const float bv = bias[e * N + gcol];
#pragma unroll
      for (int mi = 0; mi < 4; mi++) {
#pragma unroll
        for (int r = 0; r < 4; r++) {
          const int grow = m0 + wm * 64 + mi * 16 + row_hi + r;
          const float v = acc[mi][ni][r] + bv;
          const float gl = 0.5f * v * (1.0f + erff(v * 0.70710678118654752f));  // exact gelu
          Hout[((size_t)(e * C_CAP + grow)) * (size_t)N + gcol] = (__bf16)gl;
        }
      }
    }
  } else {
#pragma unroll
    for (int mi = 0; mi < 4; mi++) {
#pragma unroll
      for (int r = 0; r < 4; r++) {
        const int slot = e * C_CAP + m0 + wm * 64 + mi * 16 + row_hi + r;
        const int tok = slot_token[slot];
        if (tok < 0) continue;
        const float g = slot_gate[slot];
        const size_t trow = (size_t)tok * (size_t)N;
#pragma unroll
        for (int ni = 0; ni < 4; ni++) {
          const int gcol = n0 + wn * 64 + ni * 16 + col_lo;
          const float v = acc[mi][ni][r] + bias[e * N + gcol] + xres[trow + gcol];
          atomicAdd(&y[trow + gcol], g * v);   // <=2 adds per element
        }
      }
    }
  }
}

extern "C" void kernel_launch(void* const* d_in, const int* in_sizes, int n_in,
                              void* d_out, int out_size, void* d_ws, size_t ws_size,
                              hipStream_t stream) {
  const float* x  = (const float*)d_in[0];
  const float* wg = (const float*)d_in[1];
  const float* W1 = (const float*)d_in[2];
  const float* b1 = (const float*)d_in[3];
  const float* W2 = (const float*)d_in[4];
  const float* b2 = (const float*)d_in[5];
  float* y = (float*)d_out;

  // workspace layout (~320 MB)
  char* p = (char*)d_ws;
  __bf16* x_bf = (__bf16*)p;    p += (size_t)S_TOK * D_DIM * 2;
  __bf16* w1_bf = (__bf16*)p;   p += (size_t)E_EXP * F_DIM * D_DIM * 2;
  __bf16* w2_bf = (__bf16*)p;   p += (size_t)E_EXP * F_DIM * D_DIM * 2;
  __bf16* Hbuf = (__bf16*)p;    p += (size_t)E_EXP * C_CAP * F_DIM * 2;
  int* slot_token = (int*)p;    p += (size_t)E_EXP * C_CAP * 4;
  float* slot_gate = (float*)p; p += (size_t)E_EXP * C_CAP * 4;
  int* asg_e = (int*)p;         p += (size_t)S_TOK * 2 * 4;
  float* asg_g = (float*)p;     p += (size_t)S_TOK * 2 * 4;
  float* imp_sum = (float*)p;   p += 64;
  int* cnt_g = (int*)p;         p += 64;

  hipMemsetAsync(d_out, 0, ((size_t)S_TOK * D_DIM + 1) * sizeof(float), stream);
  hipMemsetAsync(imp_sum, 0, E_EXP * sizeof(float), stream);

  routing_kernel<<<S_TOK / 4, 256, 0, stream>>>(x, wg, x_bf, asg_e, asg_g, imp_sum);
  // W1 and W2 are contiguous inputs? No — separate pointers; but w1_bf/w2_bf are
  // contiguous in ws, so convert each with one grid (W1 then W2 halves).
  cvt_kernel<<<2048, 256, 0, stream>>>(W1, w1_bf, E_EXP * F_DIM * D_DIM / 4);
  cvt_kernel<<<2048, 256, 0, stream>>>(W2, w2_bf, E_EXP * F_DIM * D_DIM / 4);
  positions_kernel<<<1, 256, 0, stream>>>(asg_e, asg_g, imp_sum, slot_token, slot_gate,
                                          cnt_g, y + (size_t)S_TOK * D_DIM);
  moe_gemm<0><<<E_EXP * 20 * 32, 256, 0, stream>>>(x_bf, w1_bf, b1, slot_token, nullptr, nullptr,
                                                   cnt_g, Hbuf, nullptr, 20, 32, F_DIM, D_DIM);
  moe_gemm<1><<<E_EXP * 20 * 8, 256, 0, stream>>>(Hbuf, w2_bf, b2, slot_token, slot_gate, x,
                                                  cnt_g, nullptr, y, 20, 8, D_DIM, F_DIM);
}